// Round 1
// baseline (90.236 us; speedup 1.0000x reference)
//
#include <hip/hip_runtime.h>
#include <hip/hip_bf16.h>

// SpectralInverse: out[b,p,o] = sum_f cos(2*pi*(y[p]·y_w[f] + y_b[f])) * G[b,f,o] + u_b[o]
// where G[b,f,o] = (sum_m h[b,f,m] * u_w[o,m]) / n_grid   (sin(x)~=x folding, err ~1e-10)
//
// Shapes: B=4, F=128, Cin=64, Cout=8, D=3, NPTS=48^3=110592 per batch.

#define NPTS     110592
#define NFREQ    128
#define CIN      64
#define COUT     8
#define PTS_BLK  128              // points per block (main kernel)
#define BLK_PER_B (NPTS / PTS_BLK) // 864
#define LDS_STRIDE 136            // 128 + 8 bf16 pad: row stride 272B, 68 dwords (mod 32 = 4)

typedef __bf16 bf16x8 __attribute__((ext_vector_type(8)));
typedef float  f32x4  __attribute__((ext_vector_type(4)));

// ---------------------------------------------------------------------------
// Kernel 1: G[b][n][f] (o-major, padded n=16 with zeros), bf16, into workspace.
// grid = 32 blocks (b*8 + fgroup), block = 256 threads = 16 f x 16 n.
// ---------------------------------------------------------------------------
__global__ __launch_bounds__(256) void spectral_precompute_g(
    const float* __restrict__ h,      // (4,128,64)
    const float* __restrict__ u_w,    // (8,64)
    __bf16* __restrict__ gws)         // (4,16,128)
{
    int b  = blockIdx.x >> 3;
    int fg = blockIdx.x & 7;
    int t  = threadIdx.x;
    int f  = fg * 16 + (t >> 4);
    int n  = t & 15;

    float acc = 0.0f;
    if (n < COUT) {
        const float4* hp = (const float4*)(h + ((size_t)(b * NFREQ + f)) * CIN);
        const float4* up = (const float4*)(u_w + (size_t)n * CIN);
#pragma unroll
        for (int m = 0; m < CIN / 4; ++m) {
            float4 a = hp[m], c = up[m];
            acc += a.x * c.x + a.y * c.y + a.z * c.z + a.w * c.w;
        }
        acc *= (1.0f / (float)NPTS);
    }
    gws[(size_t)b * (16 * NFREQ) + n * NFREQ + f] = (__bf16)acc;
}

// ---------------------------------------------------------------------------
// Kernel 2: main. grid = 4*864 = 3456 blocks, 256 threads (4 waves).
// Each block: 128 points of one batch.
//   Phase B: compute C[p][f] = cos(2pi*Y) into LDS (bf16, padded stride).
//   Phase C: MFMA 16x16x32_bf16: (128 x 128) C  x  (128 x 16) G -> (128 x 16) U
//   Phase D: out[p][o] = U + u_b[o], o < 8.
// ---------------------------------------------------------------------------
__global__ __launch_bounds__(256, 4) void spectral_main(
    const float*  __restrict__ y,     // (4,110592,3)
    const float*  __restrict__ y_w,   // (128,3)
    const float*  __restrict__ y_b,   // (128,)
    const __bf16* __restrict__ gws,   // (4,16,128)
    const float*  __restrict__ u_b,   // (8,)
    float*        __restrict__ out)   // (4,110592,8)
{
    __shared__ __align__(16) __bf16 C_lds[PTS_BLK * LDS_STRIDE];   // 34816 B
    __shared__ __align__(16) __bf16 GT_lds[16 * LDS_STRIDE];       //  4352 B

    const int t     = threadIdx.x;
    const int blk   = blockIdx.x;
    const int b     = blk / BLK_PER_B;
    const int pbase = (blk % BLK_PER_B) * PTS_BLK;

    // ---- stage G^T (B-operand, [n][k] row-major) ----
    for (int i = t; i < 16 * NFREQ; i += 256) {
        GT_lds[(i >> 7) * LDS_STRIDE + (i & 127)] = gws[(size_t)b * (16 * NFREQ) + i];
    }

    // ---- Phase B: C generation ----
    // thread t handles f0 = (t&15)*8 .. +7  x  points p = (t>>4) + 16*j, j=0..7
    {
        const int f0   = (t & 15) * 8;
        const int prow = t >> 4;
        float w0[8], w1[8], w2[8], bb[8];
#pragma unroll
        for (int k = 0; k < 8; ++k) {
            int f = f0 + k;
            w0[k] = y_w[f * 3 + 0];
            w1[k] = y_w[f * 3 + 1];
            w2[k] = y_w[f * 3 + 2];
            bb[k] = y_b[f];
        }
        const float* yp = y + ((size_t)b * NPTS + pbase) * 3;
#pragma unroll
        for (int j = 0; j < 8; ++j) {
            int p = prow + j * 16;
            float y0 = yp[p * 3 + 0];
            float y1 = yp[p * 3 + 1];
            float y2 = yp[p * 3 + 2];
            bf16x8 cpack;
#pragma unroll
            for (int k = 0; k < 8; ++k) {
                float Y = w0[k] * y0 + w1[k] * y1 + w2[k] * y2 + bb[k];
                // cos(2*pi*Y): v_cos takes revolutions; v_fract is exact range reduction
                float c = __builtin_amdgcn_cosf(__builtin_amdgcn_fractf(Y));
                cpack[k] = (__bf16)c;
            }
            *(bf16x8*)&C_lds[p * LDS_STRIDE + f0] = cpack;
        }
    }
    __syncthreads();

    // ---- Phase C: MFMA ----
    const int lane = t & 63;
    const int wv   = t >> 6;
    const int quad = lane >> 4;
    const int l15  = lane & 15;

    f32x4 acc0 = {0.f, 0.f, 0.f, 0.f};
    f32x4 acc1 = {0.f, 0.f, 0.f, 0.f};

    const __bf16* bptr  = &GT_lds[l15 * LDS_STRIDE + quad * 8];
    const __bf16* a0ptr = &C_lds[(wv * 32 + l15) * LDS_STRIDE + quad * 8];
    const __bf16* a1ptr = a0ptr + 16 * LDS_STRIDE;

#pragma unroll
    for (int k0 = 0; k0 < NFREQ; k0 += 32) {
        bf16x8 bf = *(const bf16x8*)(bptr + k0);
        bf16x8 a0 = *(const bf16x8*)(a0ptr + k0);
        bf16x8 a1 = *(const bf16x8*)(a1ptr + k0);
        acc0 = __builtin_amdgcn_mfma_f32_16x16x32_bf16(a0, bf, acc0, 0, 0, 0);
        acc1 = __builtin_amdgcn_mfma_f32_16x16x32_bf16(a1, bf, acc1, 0, 0, 0);
    }

    // ---- Phase D: epilogue ----
    const int o = l15;
    if (o < COUT) {
        float ub = u_b[o];
        size_t base = ((size_t)b * NPTS + pbase) * COUT;
#pragma unroll
        for (int q = 0; q < 4; ++q) {
            int p0 = wv * 32 + quad * 4 + q;
            out[base + (size_t)p0 * COUT + o] = acc0[q] + ub;
            out[base + (size_t)(p0 + 16) * COUT + o] = acc1[q] + ub;
        }
    }
}

// ---------------------------------------------------------------------------
extern "C" void kernel_launch(void* const* d_in, const int* in_sizes, int n_in,
                              void* d_out, int out_size, void* d_ws, size_t ws_size,
                              hipStream_t stream)
{
    const float* h   = (const float*)d_in[0];
    const float* y   = (const float*)d_in[1];
    const float* y_w = (const float*)d_in[2];
    const float* y_b = (const float*)d_in[3];
    const float* u_w = (const float*)d_in[4];
    const float* u_b = (const float*)d_in[5];
    float* out = (float*)d_out;
    __bf16* gws = (__bf16*)d_ws;   // 4*16*128*2 = 16 KB

    spectral_precompute_g<<<32, 256, 0, stream>>>(h, u_w, gws);
    spectral_main<<<4 * BLK_PER_B, 256, 0, stream>>>(y, y_w, y_b, gws, u_b, out);
}

// Round 2
// 85.381 us; speedup vs baseline: 1.0569x; 1.0569x over previous
//
#include <hip/hip_runtime.h>
#include <hip/hip_bf16.h>

// SpectralInverse: out[b,p,o] = sum_f cos(2*pi*(y[p]·y_w[f] + y_b[f])) * G[b,f,o] + u_b[o]
// where G[b,f,o] = (sum_m h[b,f,m] * u_w[o,m]) / n_grid   (sin(x)~=x folding, err ~1e-10)
// Shapes: B=4, F=128, Cin=64, Cout=8, D=3, NPTS=48^3=110592 per batch.
//
// R2: cos computed directly into MFMA A-fragment registers (layout row=lane&15,
// k=quad*8+j — verified by R1 pass). No C tile in LDS, no phase barrier.
// Wave handles 64 points (4 row-tiles) so per-freq param reads amortize 4x.

#define NPTS      110592
#define NFREQ     128
#define CIN       64
#define COUT      8
#define PTS_BLK   256                 // points per block (4 waves x 64 pts)
#define BLK_PER_B (NPTS / PTS_BLK)    // 432
#define GT_STRIDE 136                 // bf16 elems; breaks pow2 bank stride

typedef __bf16 bf16x8 __attribute__((ext_vector_type(8)));
typedef float  f32x4  __attribute__((ext_vector_type(4)));

// ---------------------------------------------------------------------------
// Kernel 1: G[b][n][f] (o-major, n padded to 16 with zeros) bf16 into ws,
// plus packed freq params pk[f] = (w0,w1,w2,yb) float4.
// grid = 32 blocks (b*8 + fgroup), 256 threads = 16 f x 16 n.
// ---------------------------------------------------------------------------
__global__ __launch_bounds__(256) void spectral_prep(
    const float* __restrict__ h,      // (4,128,64)
    const float* __restrict__ u_w,    // (8,64)
    const float* __restrict__ y_w,    // (128,3)
    const float* __restrict__ y_b,    // (128,)
    __bf16* __restrict__ gws,         // (4,16,128)
    float4* __restrict__ pkws)        // (128,)
{
    int b  = blockIdx.x >> 3;
    int fg = blockIdx.x & 7;
    int t  = threadIdx.x;
    int f  = fg * 16 + (t >> 4);
    int n  = t & 15;

    float acc = 0.0f;
    if (n < COUT) {
        const float4* hp = (const float4*)(h + ((size_t)(b * NFREQ + f)) * CIN);
        const float4* up = (const float4*)(u_w + (size_t)n * CIN);
#pragma unroll
        for (int m = 0; m < CIN / 4; ++m) {
            float4 a = hp[m], c = up[m];
            acc += a.x * c.x + a.y * c.y + a.z * c.z + a.w * c.w;
        }
        acc *= (1.0f / (float)NPTS);
    }
    gws[(size_t)b * (16 * NFREQ) + n * NFREQ + f] = (__bf16)acc;

    if (blockIdx.x == 0 && t < NFREQ) {
        pkws[t] = make_float4(y_w[3 * t], y_w[3 * t + 1], y_w[3 * t + 2], y_b[t]);
    }
}

// ---------------------------------------------------------------------------
// Kernel 2: main. grid = 4*432 = 1728 blocks, 256 threads (4 waves).
// Wave wv: points pbase + wv*64 + rt*16 + (lane&15), rt = 0..3.
// Per k-step: build 4 A-fragments in-register (8 cos each), 1 B-frag from LDS,
// 4 MFMA. Epilogue adds u_b, stores fp32.
// ---------------------------------------------------------------------------
__global__ __launch_bounds__(256, 4) void spectral_main(
    const float*  __restrict__ y,     // (4,110592,3)
    const __bf16* __restrict__ gws,   // (4,16,128)
    const float4* __restrict__ pkws,  // (128,)
    const float*  __restrict__ u_b,   // (8,)
    float*        __restrict__ out)   // (4,110592,8)
{
    __shared__ __align__(16) __bf16 GT_lds[16 * GT_STRIDE];   // 4352 B
    __shared__ __align__(16) float4 pk_lds[NFREQ];            // 2048 B
    __shared__ __align__(16) float  y_lds[PTS_BLK * 3];       // 3072 B

    const int t     = threadIdx.x;
    const int b     = blockIdx.x / BLK_PER_B;
    const int pbase = (blockIdx.x % BLK_PER_B) * PTS_BLK;

    // ---- staging (coalesced, once per block) ----
    {
        // G^T: 2048 bf16 = 256 x bf16x8 chunks
        bf16x8 g = ((const bf16x8*)(gws + (size_t)b * (16 * NFREQ)))[t];
        *(bf16x8*)&GT_lds[(t >> 4) * GT_STRIDE + (t & 15) * 8] = g;
        if (t < NFREQ) pk_lds[t] = pkws[t];
        if (t < PTS_BLK * 3 / 4)
            ((float4*)y_lds)[t] = ((const float4*)(y + ((size_t)b * NPTS + pbase) * 3))[t];
    }
    __syncthreads();

    const int lane = t & 63;
    const int wv   = t >> 6;
    const int quad = lane >> 4;
    const int l15  = lane & 15;

    // y coords for this thread's 4 points (broadcast reads, conflict-free)
    float yc[4][3];
#pragma unroll
    for (int rt = 0; rt < 4; ++rt) {
        int p = wv * 64 + rt * 16 + l15;
        yc[rt][0] = y_lds[p * 3 + 0];
        yc[rt][1] = y_lds[p * 3 + 1];
        yc[rt][2] = y_lds[p * 3 + 2];
    }

    f32x4 acc[4] = {{0,0,0,0},{0,0,0,0},{0,0,0,0},{0,0,0,0}};
    const __bf16* bptr = &GT_lds[l15 * GT_STRIDE + quad * 8];
    const float4* wp   = &pk_lds[quad * 8];

#pragma unroll
    for (int k0 = 0; k0 < NFREQ; k0 += 32) {
        bf16x8 a0, a1, a2, a3;
#pragma unroll
        for (int j = 0; j < 8; ++j) {
            float4 w = wp[k0 + j];
            float Y0 = __builtin_fmaf(w.x, yc[0][0], __builtin_fmaf(w.y, yc[0][1], __builtin_fmaf(w.z, yc[0][2], w.w)));
            float Y1 = __builtin_fmaf(w.x, yc[1][0], __builtin_fmaf(w.y, yc[1][1], __builtin_fmaf(w.z, yc[1][2], w.w)));
            float Y2 = __builtin_fmaf(w.x, yc[2][0], __builtin_fmaf(w.y, yc[2][1], __builtin_fmaf(w.z, yc[2][2], w.w)));
            float Y3 = __builtin_fmaf(w.x, yc[3][0], __builtin_fmaf(w.y, yc[3][1], __builtin_fmaf(w.z, yc[3][2], w.w)));
            // cos(2*pi*Y): v_cos takes revolutions; v_fract is exact range reduction
            a0[j] = (__bf16)__builtin_amdgcn_cosf(__builtin_amdgcn_fractf(Y0));
            a1[j] = (__bf16)__builtin_amdgcn_cosf(__builtin_amdgcn_fractf(Y1));
            a2[j] = (__bf16)__builtin_amdgcn_cosf(__builtin_amdgcn_fractf(Y2));
            a3[j] = (__bf16)__builtin_amdgcn_cosf(__builtin_amdgcn_fractf(Y3));
        }
        bf16x8 bf = *(const bf16x8*)(bptr + k0);
        acc[0] = __builtin_amdgcn_mfma_f32_16x16x32_bf16(a0, bf, acc[0], 0, 0, 0);
        acc[1] = __builtin_amdgcn_mfma_f32_16x16x32_bf16(a1, bf, acc[1], 0, 0, 0);
        acc[2] = __builtin_amdgcn_mfma_f32_16x16x32_bf16(a2, bf, acc[2], 0, 0, 0);
        acc[3] = __builtin_amdgcn_mfma_f32_16x16x32_bf16(a3, bf, acc[3], 0, 0, 0);
    }

    // ---- epilogue: C/D layout col=lane&15, row=quad*4+reg (verified R1) ----
    if (l15 < COUT) {
        float ub = u_b[l15];
        size_t base = ((size_t)b * NPTS + pbase) * COUT;
#pragma unroll
        for (int rt = 0; rt < 4; ++rt) {
#pragma unroll
            for (int q = 0; q < 4; ++q) {
                int pr = wv * 64 + rt * 16 + quad * 4 + q;
                out[base + (size_t)pr * COUT + l15] = acc[rt][q] + ub;
            }
        }
    }
}

// ---------------------------------------------------------------------------
extern "C" void kernel_launch(void* const* d_in, const int* in_sizes, int n_in,
                              void* d_out, int out_size, void* d_ws, size_t ws_size,
                              hipStream_t stream)
{
    const float* h   = (const float*)d_in[0];
    const float* y   = (const float*)d_in[1];
    const float* y_w = (const float*)d_in[2];
    const float* y_b = (const float*)d_in[3];
    const float* u_w = (const float*)d_in[4];
    const float* u_b = (const float*)d_in[5];
    float* out = (float*)d_out;
    __bf16* gws  = (__bf16*)d_ws;                       // 16 KB
    float4* pkws = (float4*)((char*)d_ws + 16384);      //  2 KB

    spectral_prep<<<32, 256, 0, stream>>>(h, u_w, y_w, y_b, gws, pkws);
    spectral_main<<<4 * BLK_PER_B, 256, 0, stream>>>(y, gws, pkws, u_b, out);
}